// Round 1
// baseline (56.471 us; speedup 1.0000x reference)
//
#include <hip/hip_runtime.h>

// MLPDecoder: out[i,j] = sigmoid( sum_h relu(R'[i,h] + C[j,h]) * w2[h] + b2 )
// where R'[i,h] = sum_d z[i,d]*W1[h,d] + b1[h],  C[j,h] = sum_d z[j,d]*W1[h,D+d]
// N=1024, D=256, H=256. All f32.

#define NN 1024
#define DD 256
#define HH 256

// ---------------- Kernel 1: fc1 prepare ----------------
// Computes both halves as one GEMM-like pass over h' in [0, 512):
//   h' < 256 -> R'[i,h'] (with b1 folded);  h' >= 256 -> C[i,h'-256]
// grid (32 i-tiles, 8 h'-tiles), block 128. Tile 32i x 64h', 4x4 per thread.
constexpr int K1_PITCH = 68;  // pitch%4==0 for float4 LDS reads; row bank stride 4

__global__ __launch_bounds__(128) void k1_fc(const float* __restrict__ z,
                                             const float* __restrict__ W1,
                                             const float* __restrict__ b1,
                                             float* __restrict__ Rp,
                                             float* __restrict__ Cc) {
    __shared__ float zs[32][K1_PITCH];
    __shared__ float ws[64][K1_PITCH];
    const int tid = threadIdx.x;
    const int tx = tid & 15;       // h' lane: h' = h0 + 16*jj + tx
    const int ty = tid >> 4;       // i lane (0..7): i = i0 + 4*ty + ii
    const int i0 = blockIdx.x * 32;
    const int h0 = blockIdx.y * 64;
    const bool isR = (h0 < HH);
    const int wrow0 = isR ? h0 : (h0 - HH);
    const int wcol0 = isR ? 0 : DD;

    float acc[4][4] = {};

    for (int dc = 0; dc < DD; dc += 64) {
        if (dc) __syncthreads();
        // stage z tile: 32 rows x 64 cols = 512 float4; 4 per thread
        #pragma unroll
        for (int k = 0; k < 4; ++k) {
            int f = tid + k * 128;
            int r = f >> 4, c4 = f & 15;
            float4 v = *(const float4*)(z + (i0 + r) * DD + dc + c4 * 4);
            *(float4*)&zs[r][c4 * 4] = v;
        }
        // stage W1 tile: 64 rows x 64 cols = 1024 float4; 8 per thread
        #pragma unroll
        for (int k = 0; k < 8; ++k) {
            int f = tid + k * 128;
            int r = f >> 4, c4 = f & 15;
            float4 v = *(const float4*)(W1 + (wrow0 + r) * (2 * DD) + wcol0 + dc + c4 * 4);
            *(float4*)&ws[r][c4 * 4] = v;
        }
        __syncthreads();
        #pragma unroll
        for (int d4 = 0; d4 < 16; ++d4) {
            float4 za[4], wb[4];
            #pragma unroll
            for (int u = 0; u < 4; ++u) za[u] = *(const float4*)&zs[4 * ty + u][d4 * 4];
            #pragma unroll
            for (int u = 0; u < 4; ++u) wb[u] = *(const float4*)&ws[16 * u + tx][d4 * 4];
            #pragma unroll
            for (int ii = 0; ii < 4; ++ii)
                #pragma unroll
                for (int jj = 0; jj < 4; ++jj) {
                    acc[ii][jj] = fmaf(za[ii].x, wb[jj].x, acc[ii][jj]);
                    acc[ii][jj] = fmaf(za[ii].y, wb[jj].y, acc[ii][jj]);
                    acc[ii][jj] = fmaf(za[ii].z, wb[jj].z, acc[ii][jj]);
                    acc[ii][jj] = fmaf(za[ii].w, wb[jj].w, acc[ii][jj]);
                }
        }
    }

    #pragma unroll
    for (int ii = 0; ii < 4; ++ii)
        #pragma unroll
        for (int jj = 0; jj < 4; ++jj) {
            const int i = i0 + 4 * ty + ii;
            const int hp = h0 + 16 * jj + tx;
            if (isR) Rp[i * HH + hp] = acc[ii][jj] + b1[hp];
            else     Cc[i * HH + (hp - HH)] = acc[ii][jj];
        }
}

// ---------------- Kernel 2: pairwise decode ----------------
// out[i,j] = sigmoid( sum_h relu(Rp[i,h] + Cc[j,h]) * w2[h] + b2 )
// grid (32 i-tiles, 16 j-tiles) = 512 blocks, block 128 (2 waves).
// Tile 32i x 64j, 4x4 per thread. LDS h-chunks of 64.
constexpr int K2_PITCH = 68;

__global__ __launch_bounds__(128) void k2_decode(const float* __restrict__ Rp,
                                                 const float* __restrict__ Cc,
                                                 const float* __restrict__ W2,
                                                 const float* __restrict__ b2v,
                                                 float* __restrict__ out) {
    __shared__ float ra[32][K2_PITCH];
    __shared__ float ca[64][K2_PITCH];
    __shared__ float w2s[HH];
    const int tid = threadIdx.x;
    const int tx = tid & 15;       // j lane: j = j0 + 16*jj + tx
    const int ty = tid >> 4;       // i lane (0..7): i = i0 + 4*ty + ii
    const int i0 = blockIdx.x * 32;
    const int j0 = blockIdx.y * 64;

    // stage w2 once
    w2s[tid] = W2[tid];
    w2s[tid + 128] = W2[tid + 128];

    float acc[4][4] = {};

    for (int hc = 0; hc < HH; hc += 64) {
        if (hc) __syncthreads();
        // stage Rp rows i0..i0+31, cols hc..hc+63: 512 float4, 4/thread
        #pragma unroll
        for (int k = 0; k < 4; ++k) {
            int f = tid + k * 128;
            int r = f >> 4, c4 = f & 15;
            float4 v = *(const float4*)(Rp + (i0 + r) * HH + hc + c4 * 4);
            *(float4*)&ra[r][c4 * 4] = v;
        }
        // stage Cc rows j0..j0+63: 1024 float4, 8/thread
        #pragma unroll
        for (int k = 0; k < 8; ++k) {
            int f = tid + k * 128;
            int r = f >> 4, c4 = f & 15;
            float4 v = *(const float4*)(Cc + (j0 + r) * HH + hc + c4 * 4);
            *(float4*)&ca[r][c4 * 4] = v;
        }
        __syncthreads();
        #pragma unroll
        for (int h4 = 0; h4 < 16; ++h4) {
            const float4 wv = *(const float4*)&w2s[hc + h4 * 4];
            float4 rA[4], rC[4];
            #pragma unroll
            for (int u = 0; u < 4; ++u) rA[u] = *(const float4*)&ra[4 * ty + u][h4 * 4];
            #pragma unroll
            for (int u = 0; u < 4; ++u) rC[u] = *(const float4*)&ca[16 * u + tx][h4 * 4];
            #pragma unroll
            for (int ii = 0; ii < 4; ++ii)
                #pragma unroll
                for (int jj = 0; jj < 4; ++jj) {
                    float s0 = rA[ii].x + rC[jj].x;
                    float s1 = rA[ii].y + rC[jj].y;
                    float s2 = rA[ii].z + rC[jj].z;
                    float s3 = rA[ii].w + rC[jj].w;
                    acc[ii][jj] = fmaf(fmaxf(s0, 0.f), wv.x, acc[ii][jj]);
                    acc[ii][jj] = fmaf(fmaxf(s1, 0.f), wv.y, acc[ii][jj]);
                    acc[ii][jj] = fmaf(fmaxf(s2, 0.f), wv.z, acc[ii][jj]);
                    acc[ii][jj] = fmaf(fmaxf(s3, 0.f), wv.w, acc[ii][jj]);
                }
        }
    }

    const float b2s = b2v[0];
    #pragma unroll
    for (int ii = 0; ii < 4; ++ii)
        #pragma unroll
        for (int jj = 0; jj < 4; ++jj) {
            const int i = i0 + 4 * ty + ii;
            const int j = j0 + 16 * jj + tx;
            const float x = acc[ii][jj] + b2s;
            out[i * NN + j] = 1.0f / (1.0f + __expf(-x));
        }
}

extern "C" void kernel_launch(void* const* d_in, const int* in_sizes, int n_in,
                              void* d_out, int out_size, void* d_ws, size_t ws_size,
                              hipStream_t stream) {
    const float* z  = (const float*)d_in[0];
    const float* W1 = (const float*)d_in[1];
    const float* b1 = (const float*)d_in[2];
    const float* W2 = (const float*)d_in[3];
    const float* b2 = (const float*)d_in[4];
    float* out = (float*)d_out;

    float* Rp = (float*)d_ws;              // [1024][256]
    float* Cc = Rp + NN * HH;              // [1024][256]

    k1_fc<<<dim3(32, 8), 128, 0, stream>>>(z, W1, b1, Rp, Cc);
    k2_decode<<<dim3(32, 16), 128, 0, stream>>>(Rp, Cc, W2, b2, out);
}

// Round 2
// 48.704 us; speedup vs baseline: 1.1595x; 1.1595x over previous
//
#include <hip/hip_runtime.h>

#define NN 1024
#define DD 256
#define HH 256

typedef __attribute__((ext_vector_type(8))) short short8;
typedef __attribute__((ext_vector_type(4))) float floatx4;

// ---- ws layout (bytes) ----
#define ZB_OFF   0u           // bf16 zb[1024][256]            512 KiB
#define WC_OFF   524288u      // bf16 Wcat[528][256]           264 KiB (row 512 = wc, 513..527 = 0)
#define B1F_OFF  802816u      // f32 b1f[528]
#define PV_OFF   806912u      // int P (count of w2>0)
#define RT_OFF   1048576u     // f32 Rt[1024][256]  (= (z@W1row^T + b1)*|w2|, h-permuted)
#define CN_OFF   2097152u     // f32 Cn[1024][256]  (= -(z@W1col^T)*|w2|, h-permuted)
#define K_OFF    3145728u     // f32 K[1024]  (= z@wc + b2)
#define P0_OFF   3211264u     // f32 partial 0 [1024][1024]
#define P1_OFF   7405568u     // f32 partial 1 [1024][1024]
#define WS_SPLIT_NEED 11599872u

__device__ __forceinline__ unsigned short f2bf(float x) {  // RNE f32->bf16
  unsigned u = __float_as_uint(x);
  return (unsigned short)((u + 0x7FFFu + ((u >> 16) & 1u)) >> 16);
}

// ---------------- k0: prep (z->bf16, Wcat permuted+scaled, wc row, b1f, P) ----------------
__global__ __launch_bounds__(256) void k0_prep(const float* __restrict__ z,
    const float* __restrict__ W1, const float* __restrict__ b1,
    const float* __restrict__ W2, const float* __restrict__ b2,
    char* __restrict__ ws) {
  const int b = blockIdx.x, t = threadIdx.x;
  unsigned short* zb = (unsigned short*)(ws + ZB_OFF);
  unsigned short* Wc = (unsigned short*)(ws + WC_OFF);
  float* b1f = (float*)(ws + B1F_OFF);

  if (b < 256) {                       // z -> bf16, 1 float4 per thread
    const int g = b * 256 + t;
    float4 v = ((const float4*)z)[g];
    ushort4 u;
    u.x = f2bf(v.x); u.y = f2bf(v.y); u.z = f2bf(v.z); u.w = f2bf(v.w);
    ((ushort4*)zb)[g] = u;
    return;
  }
  if (b < 384) {                       // Wcat rows q = 4*(b-256)+(t>>6), permuted & scaled
    __shared__ unsigned long long masks[4];
    __shared__ short inv[256];
    const bool pos = W2[t] > 0.f;
    unsigned long long m = __ballot(pos);
    if ((t & 63) == 0) masks[t >> 6] = m;
    __syncthreads();
    int P = 0;
    #pragma unroll
    for (int w = 0; w < 4; ++w) P += __popcll(masks[w]);
    const int w = t >> 6;
    int below = __popcll(masks[w] & ((1ull << (t & 63)) - 1ull));
    #pragma unroll
    for (int wi = 0; wi < 4; ++wi) if (wi < w) below += __popcll(masks[wi]);
    const int dest = pos ? below : (P + t - below);
    inv[dest] = (short)t;
    __syncthreads();

    const int q = (b - 256) * 4 + (t >> 6);     // 0..511
    const int d0 = (t & 63) * 4;
    const int oh = inv[q & 255];
    const bool top = q < 256;
    const float wa = fabsf(W2[oh]);
    const float sc = top ? wa : -wa;            // negate the col-part -> Cn = -C~
    const float4 v = *(const float4*)(W1 + oh * 512 + (top ? 0 : 256) + d0);
    ushort4 u;
    u.x = f2bf(v.x * sc); u.y = f2bf(v.y * sc); u.z = f2bf(v.z * sc); u.w = f2bf(v.w * sc);
    ((ushort4*)(Wc + q * 256))[d0 >> 2] = u;
    if (d0 == 0) b1f[q] = top ? b1[oh] * wa : 0.f;
    if (b == 256 && t == 0) *(int*)(ws + PV_OFF) = P;
    return;
  }
  // b in [384,388): wc quarter (64 d-columns each): wc[d] = sum_h W2[h]*W1[h][256+d]
  {
    __shared__ float part[4][64];
    const int w = t >> 6, dl = t & 63;
    const int d = (b - 384) * 64 + dl;
    float acc = 0.f;
    const float* col = W1 + 256 + d;
    #pragma unroll 8
    for (int h = w * 64; h < w * 64 + 64; ++h) acc += W2[h] * col[h * 512];
    part[w][dl] = acc;
    __syncthreads();
    if (w == 0) {
      float s = part[0][dl] + part[1][dl] + part[2][dl] + part[3][dl];
      Wc[512 * 256 + d] = f2bf(s);
    }
    if (b == 384) {
      for (int r = 513; r < 528; ++r) Wc[r * 256 + t] = 0;   // zero pad rows
      if (t == 0) b1f[512] = b2[0];
      if (t < 15) b1f[513 + t] = 0.f;
    }
  }
}

// ---------------- k1: fc1 GEMM via bf16 MFMA ----------------
// G[i][q] = zb[i][:] . Wcat[q][:] + b1f[q]; q<256 -> Rt, q<512 -> Cn, q-tile 32 -> K (col 0)
__global__ __launch_bounds__(64) void k1_mfma(char* __restrict__ ws) {
  const unsigned short* zb = (const unsigned short*)(ws + ZB_OFF);
  const unsigned short* Wc = (const unsigned short*)(ws + WC_OFF);
  const float* b1f = (const float*)(ws + B1F_OFF);
  float* Rt = (float*)(ws + RT_OFF);
  float* Cn = (float*)(ws + CN_OFF);
  float* Kv = (float*)(ws + K_OFF);

  const int l = threadIdx.x;
  const int i0 = blockIdx.x * 16, q0 = blockIdx.y * 16;
  const short* A = (const short*)zb + (i0 + (l & 15)) * 256 + ((l >> 4) * 8);
  const short* B = (const short*)Wc + (q0 + (l & 15)) * 256 + ((l >> 4) * 8);
  floatx4 acc = {0.f, 0.f, 0.f, 0.f};
  #pragma unroll
  for (int kk = 0; kk < 8; ++kk) {
    short8 a  = *(const short8*)(A + kk * 32);
    short8 bb = *(const short8*)(B + kk * 32);
    acc = __builtin_amdgcn_mfma_f32_16x16x32_bf16(a, bb, acc, 0, 0, 0);
  }
  const int col = l & 15, r0 = (l >> 4) * 4;   // D: col=lane&15, row=(lane>>4)*4+reg
  if (q0 < 512) {
    const float bias = b1f[q0 + col];
    if (q0 < 256) {
      #pragma unroll
      for (int q = 0; q < 4; ++q) Rt[(i0 + r0 + q) * 256 + q0 + col] = acc[q] + bias;
    } else {
      #pragma unroll
      for (int q = 0; q < 4; ++q) Cn[(i0 + r0 + q) * 256 + (q0 - 256) + col] = acc[q] + bias;
    }
  } else if (col == 0) {
    const float bias = b1f[512];               // = b2
    #pragma unroll
    for (int q = 0; q < 4; ++q) Kv[i0 + r0 + q] = acc[q] + bias;
  }
}

// ---------------- k2: pairwise max/accumulate ----------------
// partial[i,j] = sum_{h<P} max(Rt,Cn) - sum_{h>=P} max(Rt,Cn)  over this block's h-range.
// 1-wave blocks, 16i x 64j tile, LDS 20KB (8 blocks/CU), global_load_lds double-buffered,
// XOR-swizzle via pre-swizzled global source + swizzled read (2-way bank alias = free).
template<int HS>
__global__ __launch_bounds__(64) void k2_pair(const float* __restrict__ Rt,
    const float* __restrict__ Cn, const float* __restrict__ Kv,
    const int* __restrict__ Pp, float* __restrict__ P0,
    float* __restrict__ P1, float* __restrict__ out) {
  __shared__ __align__(16) char lds[20480];  // ca[2][64][32]f32 @0, ra[2][16][32]f32 @16384
  const int l = threadIdx.x;
  const int tx = l & 15, ty = l >> 4;
  const int i0 = blockIdx.x * 16, j0 = blockIdx.y * 64;
  const int hbase = blockIdx.z * (HH / HS);
  constexpr int NCH = (HH / HS) / 32;
  const int Pv = Pp[0];

  const int srow = l >> 3;                    // row-within-8 for staging
  const int sx = ((l & 7) ^ srow) * 4;        // pre-swizzled source column offset
  const float* caSrc = Cn + (j0 + srow) * 256 + sx;
  const float* raSrc = Rt + (i0 + srow) * 256 + sx;

#define STAGE(bb, hc) do { \
    _Pragma("unroll") \
    for (int c = 0; c < 8; ++c) \
      __builtin_amdgcn_global_load_lds( \
        (const __attribute__((address_space(1))) unsigned int*)(caSrc + c * 2048 + (hc)), \
        (__attribute__((address_space(3))) unsigned int*)(lds + (bb) * 8192 + c * 1024), 16, 0, 0); \
    _Pragma("unroll") \
    for (int a = 0; a < 2; ++a) \
      __builtin_amdgcn_global_load_lds( \
        (const __attribute__((address_space(1))) unsigned int*)(raSrc + a * 2048 + (hc)), \
        (__attribute__((address_space(3))) unsigned int*)(lds + 16384 + (bb) * 2048 + a * 1024), 16, 0, 0); \
  } while (0)

  int caB[4], raB[4];
  #pragma unroll
  for (int u = 0; u < 4; ++u) caB[u] = (16 * u + tx) * 128 + ((tx & 7) << 4);
  #pragma unroll
  for (int ii = 0; ii < 4; ++ii) {
    const int r = 4 * ty + ii;
    raB[ii] = 16384 + r * 128 + ((r & 7) << 4);
  }

  float acc[4][4] = {};

  auto compute = [&](int buf, int hc) {
    const int cao = buf * 8192, rao = buf * 2048;
    #pragma unroll
    for (int h4 = 0; h4 < 8; ++h4) {
      float4 rC[4], rA[4];
      #pragma unroll
      for (int u = 0; u < 4; ++u)
        rC[u] = *(const float4*)(lds + ((caB[u] + cao) ^ (h4 << 4)));
      #pragma unroll
      for (int ii = 0; ii < 4; ++ii)
        rA[ii] = *(const float4*)(lds + ((raB[ii] + rao) ^ (h4 << 4)));
      const int ha = hc + h4 * 4;
      const float s0 = (ha + 0 < Pv) ? 1.f : -1.f;
      const float s1 = (ha + 1 < Pv) ? 1.f : -1.f;
      const float s2 = (ha + 2 < Pv) ? 1.f : -1.f;
      const float s3 = (ha + 3 < Pv) ? 1.f : -1.f;
      #pragma unroll
      for (int ii = 0; ii < 4; ++ii)
        #pragma unroll
        for (int u = 0; u < 4; ++u) {
          acc[ii][u] = fmaf(fmaxf(rA[ii].x, rC[u].x), s0, acc[ii][u]);
          acc[ii][u] = fmaf(fmaxf(rA[ii].y, rC[u].y), s1, acc[ii][u]);
          acc[ii][u] = fmaf(fmaxf(rA[ii].z, rC[u].z), s2, acc[ii][u]);
          acc[ii][u] = fmaf(fmaxf(rA[ii].w, rC[u].w), s3, acc[ii][u]);
        }
    }
  };

  STAGE(0, hbase);
  int buf = 0;
  #pragma unroll 1
  for (int t = 0; t < NCH - 1; ++t) {
    STAGE(buf ^ 1, hbase + (t + 1) * 32);
    asm volatile("s_waitcnt vmcnt(10)" ::: "memory");  // wait current chunk, keep next in flight
    compute(buf, hbase + t * 32);
    buf ^= 1;
  }
  asm volatile("s_waitcnt vmcnt(0)" ::: "memory");
  compute(buf, hbase + (NCH - 1) * 32);

  if (HS == 2) {
    float* Pz = (blockIdx.z == 0) ? P0 : P1;
    #pragma unroll
    for (int ii = 0; ii < 4; ++ii)
      #pragma unroll
      for (int u = 0; u < 4; ++u)
        Pz[(i0 + 4 * ty + ii) * NN + j0 + 16 * u + tx] = acc[ii][u];
  } else {
    #pragma unroll
    for (int u = 0; u < 4; ++u) {
      const float kq = Kv[j0 + 16 * u + tx];
      #pragma unroll
      for (int ii = 0; ii < 4; ++ii) {
        const float x = acc[ii][u] + kq;
        out[(i0 + 4 * ty + ii) * NN + j0 + 16 * u + tx] = 1.f / (1.f + __expf(-x));
      }
    }
  }
#undef STAGE
}

// ---------------- k3: combine + sigmoid ----------------
__global__ __launch_bounds__(256) void k3_fin(const float* __restrict__ P0,
    const float* __restrict__ P1, const float* __restrict__ Kv,
    float* __restrict__ out) {
  const int g = blockIdx.x * 256 + threadIdx.x;  // float4 index
  const float4 a = ((const float4*)P0)[g];
  const float4 b = ((const float4*)P1)[g];
  const float4 k = *(const float4*)(Kv + ((g * 4) & 1023));
  float4 o;
  o.x = 1.f / (1.f + __expf(-(a.x + b.x + k.x)));
  o.y = 1.f / (1.f + __expf(-(a.y + b.y + k.y)));
  o.z = 1.f / (1.f + __expf(-(a.z + b.z + k.z)));
  o.w = 1.f / (1.f + __expf(-(a.w + b.w + k.w)));
  ((float4*)out)[g] = o;
}

extern "C" void kernel_launch(void* const* d_in, const int* in_sizes, int n_in,
                              void* d_out, int out_size, void* d_ws, size_t ws_size,
                              hipStream_t stream) {
  const float* z  = (const float*)d_in[0];
  const float* W1 = (const float*)d_in[1];
  const float* b1 = (const float*)d_in[2];
  const float* W2 = (const float*)d_in[3];
  const float* b2 = (const float*)d_in[4];
  float* out = (float*)d_out;
  char* ws = (char*)d_ws;

  k0_prep<<<388, 256, 0, stream>>>(z, W1, b1, W2, b2, ws);
  k1_mfma<<<dim3(64, 33), 64, 0, stream>>>(ws);

  const float* Rt = (const float*)(ws + RT_OFF);
  const float* Cn = (const float*)(ws + CN_OFF);
  const float* Kv = (const float*)(ws + K_OFF);
  const int*   Pp = (const int*)(ws + PV_OFF);

  if (ws_size >= WS_SPLIT_NEED) {
    float* P0 = (float*)(ws + P0_OFF);
    float* P1 = (float*)(ws + P1_OFF);
    k2_pair<2><<<dim3(64, 16, 2), 64, 0, stream>>>(Rt, Cn, Kv, Pp, P0, P1, out);
    k3_fin<<<1024, 256, 0, stream>>>(P0, P1, Kv, out);
  } else {
    k2_pair<1><<<dim3(64, 16, 1), 64, 0, stream>>>(Rt, Cn, Kv, Pp, nullptr, nullptr, out);
  }
}

// Round 3
// 46.087 us; speedup vs baseline: 1.2253x; 1.0568x over previous
//
#include <hip/hip_runtime.h>

#define NN 1024
#define DD 256
#define HH 256

typedef __attribute__((ext_vector_type(8))) short short8;
typedef __attribute__((ext_vector_type(4))) float floatx4;
typedef _Float16 h2v __attribute__((ext_vector_type(2)));

// ---- ws layout (bytes) ----
#define ZB_OFF   0u           // bf16 zb[1024][256]            512 KiB
#define WC_OFF   524288u      // bf16 Wcat[528][256]           264 KiB (row 512 = wc, 513..527 = 0)
#define B1F_OFF  802816u      // f32 b1f[528]
#define PV_OFF   806912u      // int P (count of w2>0)
#define RH_OFF   1048576u     // f16 Rh[1024][256]  (= (z@W1row^T + b1)*|w2|, h-permuted)   512 KiB
#define C4_OFF   1572864u     // uint4 C4[32][1024]: pair-packed transposed -C~ (f16)        512 KiB
#define KV_OFF   2097152u     // f32 Kv[1024]  (= z@wc + b2)

__device__ __forceinline__ unsigned short f2bf(float x) {  // RNE f32->bf16
  unsigned u = __float_as_uint(x);
  return (unsigned short)((u + 0x7FFFu + ((u >> 16) & 1u)) >> 16);
}

// packed max + packed dot into f32 acc: 2 h-values per call, 2 VALU instr
__device__ __forceinline__ float pmaxdot(unsigned r, unsigned c, unsigned m, float acc) {
  h2v a = __builtin_bit_cast(h2v, r);
  h2v b = __builtin_bit_cast(h2v, c);
#if __has_builtin(__builtin_elementwise_max)
  h2v mx = __builtin_elementwise_max(a, b);
#else
  h2v mx;
  mx[0] = a[0] > b[0] ? a[0] : b[0];
  mx[1] = a[1] > b[1] ? a[1] : b[1];
#endif
#if __has_builtin(__builtin_amdgcn_fdot2)
  return __builtin_amdgcn_fdot2(mx, __builtin_bit_cast(h2v, m), acc, false);
#else
  h2v sv = __builtin_bit_cast(h2v, m);
  acc = fmaf((float)mx[0], (float)sv[0], acc);
  return fmaf((float)mx[1], (float)sv[1], acc);
#endif
}

// ---------------- k0: prep (z->bf16, Wcat permuted+scaled, wc row, b1f, P) ----------------
__global__ __launch_bounds__(256) void k0_prep(const float* __restrict__ z,
    const float* __restrict__ W1, const float* __restrict__ b1,
    const float* __restrict__ W2, const float* __restrict__ b2,
    char* __restrict__ ws) {
  const int b = blockIdx.x, t = threadIdx.x;
  unsigned short* zb = (unsigned short*)(ws + ZB_OFF);
  unsigned short* Wc = (unsigned short*)(ws + WC_OFF);
  float* b1f = (float*)(ws + B1F_OFF);

  if (b < 256) {                       // z -> bf16, 1 float4 per thread
    const int g = b * 256 + t;
    float4 v = ((const float4*)z)[g];
    ushort4 u;
    u.x = f2bf(v.x); u.y = f2bf(v.y); u.z = f2bf(v.z); u.w = f2bf(v.w);
    ((ushort4*)zb)[g] = u;
    return;
  }
  if (b < 384) {                       // Wcat rows q = 4*(b-256)+(t>>6), permuted & scaled
    __shared__ unsigned long long masks[4];
    __shared__ short inv[256];
    const bool pos = W2[t] > 0.f;
    unsigned long long m = __ballot(pos);
    if ((t & 63) == 0) masks[t >> 6] = m;
    __syncthreads();
    int P = 0;
    #pragma unroll
    for (int w = 0; w < 4; ++w) P += __popcll(masks[w]);
    const int w = t >> 6;
    int below = __popcll(masks[w] & ((1ull << (t & 63)) - 1ull));
    #pragma unroll
    for (int wi = 0; wi < 4; ++wi) if (wi < w) below += __popcll(masks[wi]);
    const int dest = pos ? below : (P + t - below);
    inv[dest] = (short)t;
    __syncthreads();

    const int q = (b - 256) * 4 + (t >> 6);     // 0..511
    const int d0 = (t & 63) * 4;
    const int oh = inv[q & 255];
    const bool top = q < 256;
    const float wa = fabsf(W2[oh]);
    const float sc = top ? wa : -wa;            // negate the col-part -> Cn = -C~
    const float4 v = *(const float4*)(W1 + oh * 512 + (top ? 0 : 256) + d0);
    ushort4 u;
    u.x = f2bf(v.x * sc); u.y = f2bf(v.y * sc); u.z = f2bf(v.z * sc); u.w = f2bf(v.w * sc);
    ((ushort4*)(Wc + q * 256))[d0 >> 2] = u;
    if (d0 == 0) b1f[q] = top ? b1[oh] * wa : 0.f;
    if (b == 256 && t == 0) *(int*)(ws + PV_OFF) = P;
    return;
  }
  // b in [384,388): wc quarter (64 d-columns each): wc[d] = sum_h W2[h]*W1[h][256+d]
  {
    __shared__ float part[4][64];
    const int w = t >> 6, dl = t & 63;
    const int d = (b - 384) * 64 + dl;
    float acc = 0.f;
    const float* col = W1 + 256 + d;
    #pragma unroll 8
    for (int h = w * 64; h < w * 64 + 64; ++h) acc += W2[h] * col[h * 512];
    part[w][dl] = acc;
    __syncthreads();
    if (w == 0) {
      float s = part[0][dl] + part[1][dl] + part[2][dl] + part[3][dl];
      Wc[512 * 256 + d] = f2bf(s);
    }
    if (b == 384) {
      for (int r = 513; r < 528; ++r) Wc[r * 256 + t] = 0;   // zero pad rows
      if (t == 0) b1f[512] = b2[0];
      if (t < 15) b1f[513 + t] = 0.f;
    }
  }
}

// ---------------- k1: fc1 GEMM via bf16 MFMA -> f16 outputs ----------------
// G[i][q] = zb[i][:] . Wcat[q][:] + b1f[q]
//   q<256  -> Rh[i][q] f16 (row-major)
//   q<512  -> C4 (pair-packed f16, transposed: uint4 C4[g][j] = pairs 4g..4g+3 of column j)
//   q-tile 32 -> Kv (f32, col 0)
__global__ __launch_bounds__(64) void k1_mfma(char* __restrict__ ws) {
  __shared__ unsigned short tileh[16][16];
  const unsigned short* zb = (const unsigned short*)(ws + ZB_OFF);
  const unsigned short* Wcu = (const unsigned short*)(ws + WC_OFF);
  const float* b1f = (const float*)(ws + B1F_OFF);
  _Float16* Rh = (_Float16*)(ws + RH_OFF);
  uint4* C4 = (uint4*)(ws + C4_OFF);
  float* Kv = (float*)(ws + KV_OFF);

  const int l = threadIdx.x;
  const int i0 = blockIdx.x * 16, q0 = blockIdx.y * 16;
  const short* A = (const short*)zb + (i0 + (l & 15)) * 256 + ((l >> 4) * 8);
  const short* B = (const short*)Wcu + (q0 + (l & 15)) * 256 + ((l >> 4) * 8);
  floatx4 acc = {0.f, 0.f, 0.f, 0.f};
  #pragma unroll
  for (int kk = 0; kk < 8; ++kk) {
    short8 a  = *(const short8*)(A + kk * 32);
    short8 bb = *(const short8*)(B + kk * 32);
    acc = __builtin_amdgcn_mfma_f32_16x16x32_bf16(a, bb, acc, 0, 0, 0);
  }
  const int col = l & 15, r0 = (l >> 4) * 4;   // D: col=lane&15, row=(lane>>4)*4+reg
  if (q0 < 256) {
    const float bias = b1f[q0 + col];
    #pragma unroll
    for (int q = 0; q < 4; ++q)
      Rh[(i0 + r0 + q) * 256 + q0 + col] = (_Float16)(acc[q] + bias);
  } else if (q0 < 512) {
    // C-part: value already = -|w2|*C (scaling folded in Wcat), bias 0.
    #pragma unroll
    for (int q = 0; q < 4; ++q)
      tileh[r0 + q][col] = __builtin_bit_cast(unsigned short, (_Float16)acc[q]);
    __syncthreads();
    if (l < 32) {
      const int gg = l >> 4, jl = l & 15;          // gg: which 8-h half; jl: local j
      const unsigned* row = (const unsigned*)&tileh[jl][0];   // 8 u32 pairs
      uint4 v;
      v.x = row[gg * 4 + 0]; v.y = row[gg * 4 + 1];
      v.z = row[gg * 4 + 2]; v.w = row[gg * 4 + 3];
      C4[((q0 - 256) / 8 + gg) * 1024 + (i0 + jl)] = v;
    }
  } else if (col == 0) {
    const float bias = b1f[512];                   // = b2
    #pragma unroll
    for (int q = 0; q < 4; ++q) Kv[i0 + r0 + q] = acc[q] + bias;
  }
}

// ---------------- k2: pairwise decode, LDS-free ----------------
// lane = j; C pairs in VGPR (per 64-h chunk); R rows via uniform (scalar) loads.
// out[i,j] = sigmoid( sum_pairs dot2(pk_max(Rpair, Cpair), sgn_pair) + Kv[j] )
__global__ __launch_bounds__(64) void k2_pair(const char* __restrict__ ws,
                                              float* __restrict__ out) {
  const int lane = threadIdx.x;
  const int i0 = blockIdx.x * 8;
  const int j  = blockIdx.y * 64 + lane;
  const _Float16* Rh = (const _Float16*)(ws + RH_OFF);
  const uint4* C4 = (const uint4*)(ws + C4_OFF);
  const float* Kv = (const float*)(ws + KV_OFF);
  const int P = *(const int*)(ws + PV_OFF);

  float acc[8] = {};
  uint4 cc[8], cn[8];
  #pragma unroll
  for (int g = 0; g < 8; ++g) cc[g] = C4[g * 1024 + j];

  #pragma unroll 1
  for (int ch = 0; ch < 4; ++ch) {
    if (ch < 3) {
      #pragma unroll
      for (int g = 0; g < 8; ++g) cn[g] = C4[((ch + 1) * 8 + g) * 1024 + j];
    }
    // multipliers (lane-invariant): +1 pairs below P, -1 above; one mixed chunk max
    unsigned mulU[32];
    const int c0 = ch * 64;
    if (c0 + 64 <= P) {
      #pragma unroll
      for (int p = 0; p < 32; ++p) mulU[p] = 0x3C003C00u;
    } else if (c0 >= P) {
      #pragma unroll
      for (int p = 0; p < 32; ++p) mulU[p] = 0xBC00BC00u;
    } else {
      #pragma unroll
      for (int p = 0; p < 32; ++p) {
        const int h0 = c0 + 2 * p;
        const unsigned lo = (h0 < P) ? 0x3C00u : 0xBC00u;
        const unsigned hi = (h0 + 1 < P) ? 0x3C00u : 0xBC00u;
        mulU[p] = lo | (hi << 16);
      }
    }
    #pragma unroll
    for (int i = 0; i < 8; ++i) {
      const unsigned* rr = (const unsigned*)(Rh + (i0 + i) * 256 + ch * 64);
      float a = acc[i];
      #pragma unroll
      for (int g = 0; g < 8; ++g) {
        const uint4 c = cc[g];
        a = pmaxdot(rr[4 * g + 0], c.x, mulU[4 * g + 0], a);
        a = pmaxdot(rr[4 * g + 1], c.y, mulU[4 * g + 1], a);
        a = pmaxdot(rr[4 * g + 2], c.z, mulU[4 * g + 2], a);
        a = pmaxdot(rr[4 * g + 3], c.w, mulU[4 * g + 3], a);
      }
      acc[i] = a;
    }
    if (ch < 3) {
      #pragma unroll
      for (int g = 0; g < 8; ++g) cc[g] = cn[g];
    }
  }

  const float kv = Kv[j];
  #pragma unroll
  for (int i = 0; i < 8; ++i) {
    const float x = acc[i] + kv;
    out[(i0 + i) * NN + j] = 1.f / (1.f + __expf(-x));
  }
}

extern "C" void kernel_launch(void* const* d_in, const int* in_sizes, int n_in,
                              void* d_out, int out_size, void* d_ws, size_t ws_size,
                              hipStream_t stream) {
  const float* z  = (const float*)d_in[0];
  const float* W1 = (const float*)d_in[1];
  const float* b1 = (const float*)d_in[2];
  const float* W2 = (const float*)d_in[3];
  const float* b2 = (const float*)d_in[4];
  float* out = (float*)d_out;
  char* ws = (char*)d_ws;

  k0_prep<<<388, 256, 0, stream>>>(z, W1, b1, W2, b2, ws);
  k1_mfma<<<dim3(64, 33), 64, 0, stream>>>(ws);
  k2_pair<<<dim3(128, 16), 64, 0, stream>>>(ws, out);
}